// Round 1
// baseline (542.124 us; speedup 1.0000x reference)
//
#include <hip/hip_runtime.h>

// TensorConvolutionTrainLayer: S=512,P=196,Q=48,CB=8,R=32,C=10,N=8
// Strategy: everything matmul-shaped runs through one templated f16-MFMA GEMM
// C[M][N] = A[M][K] @ Bt[N][K]^T  (both operands K-major, K padded to mult of 32)
//   GEMM1 (MODE0): Mt[row][(s,p)] = Ckt[row][q] @ xh[(s,p)][q]^T   (all 8 carriages at once)
//   GEMM2 (MODE1): G[(ab,s)][lr]  = Mt_k[(ab,s)][p] @ Akr[lr][p]^T (the 6.6 GMAC/step hot op)
//   state0 (MODE2), GN (MODE3): same template, different epilogues
// state update (contract G with state over a,l) is a cheap fp32 vector kernel.

typedef _Float16 half8 __attribute__((ext_vector_type(8)));
typedef float floatx4 __attribute__((ext_vector_type(4)));

#define KP 224   // P=196 padded to 7*32
#define QP 64    // Q=48 padded to 2*32
#define NROWS 400 // Ckt rows: 8 (first) + 6*64 (mid) + 8 (last)
#define BM 128
#define BN 128
#define BK 32

__device__ __forceinline__ void gld_lds16(const void* g, void* l) {
  __builtin_amdgcn_global_load_lds((const __attribute__((address_space(1))) void*)g,
                                   (__attribute__((address_space(3))) void*)l, 16, 0, 0);
}

// ---------------- generic MFMA GEMM ----------------
// A: [Mrows][K] f16 row-major, Bt: [N][K] f16 row-major. 128x128 tile, 4 waves.
template<int K, int MODE>
__global__ __launch_bounds__(256)
void gemm_mfma(const _Float16* __restrict__ A, const _Float16* __restrict__ Bt,
               void* __restrict__ outp)
{
  __shared__ __align__(16) _Float16 Ash[BM * BK];
  __shared__ __align__(16) _Float16 Bsh[BN * BK];
  const int tid  = threadIdx.x;
  const int wave = tid >> 6;
  const int lane = tid & 63;
  const int m0 = blockIdx.y * BM;
  const int n0 = blockIdx.x * BN;
  const int wm = (wave >> 1) * 64;
  const int wn = (wave & 1) * 64;
  const int fr = lane & 15;   // frag 16-row
  const int fq = lane >> 4;   // quad -> k-chunk of 8 (A/B symmetric; k-perm cancels)

  floatx4 acc[4][4] = {};

  for (int kt = 0; kt < K; kt += BK) {
    __syncthreads();
    // stage 128x32 halfs (8KB) per matrix = 512 chunks of 16B; 2 chunks/thread each
#pragma unroll
    for (int j = 0; j < 2; j++) {
      const int c   = j * 256 + tid;
      const int row = c >> 2;
      const int ko  = (c & 3) * 8;
      // LDS dest: wave-uniform base + lane*16 (chunk c == wave*64+lane+j*256)
      gld_lds16(A  + (size_t)(m0 + row) * K + kt + ko,
                (char*)Ash + (size_t)(j * 256 + wave * 64) * 16);
      gld_lds16(Bt + (size_t)(n0 + row) * K + kt + ko,
                (char*)Bsh + (size_t)(j * 256 + wave * 64) * 16);
    }
    __syncthreads();
    half8 af[4], bf[4];
#pragma unroll
    for (int i = 0; i < 4; i++)
      af[i] = *(const half8*)&Ash[(wm + i * 16 + fr) * BK + fq * 8];
#pragma unroll
    for (int i = 0; i < 4; i++)
      bf[i] = *(const half8*)&Bsh[(wn + i * 16 + fr) * BK + fq * 8];
#pragma unroll
    for (int i = 0; i < 4; i++)
#pragma unroll
      for (int j = 0; j < 4; j++)
        acc[i][j] = __builtin_amdgcn_mfma_f32_16x16x32_f16(af[i], bf[j], acc[i][j], 0, 0, 0);
  }

  // epilogue: C/D layout col = lane&15, row = quad*4 + reg  [measured m89/m91]
#pragma unroll
  for (int i = 0; i < 4; i++) {
#pragma unroll
    for (int j = 0; j < 4; j++) {
#pragma unroll
      for (int r = 0; r < 4; r++) {
        const int m = m0 + wm + i * 16 + fq * 4 + r;
        const int n = n0 + wn + j * 16 + fr;
        const float v = acc[i][j][r];
        if constexpr (MODE == 0) {
          // Mt[row][s][p224]; col n = s*196+p
          if (m < NROWS) {
            const unsigned s = (unsigned)n / 196u;
            const unsigned p = (unsigned)n - s * 196u;
            ((_Float16*)outp)[((size_t)m * 512 + s) * KP + p] = (_Float16)v;
          }
        } else if constexpr (MODE == 1) {
          ((_Float16*)outp)[(size_t)m * 1024 + n] = (_Float16)v;     // G[(ab,s)][lr]
        } else if constexpr (MODE == 2) {
          // state0: m = b*512+s, n = r*10+c -> St[s][b][r][c]
          if (n < 320)
            ((float*)outp)[(size_t)(m & 511) * 2560 + (m >> 9) * 320 + n] = v;
        } else {
          // GN: m = a*512+s, n = l -> GN[a][s][l]
          if (n < 32)
            ((float*)outp)[(size_t)m * 32 + n] = v;
        }
      }
    }
  }
}

// ---------------- state update: NS[s,b,r,c] = sum_{a,l} St[s,a,l,c] * G[(a8+b)*512+s][l*32+r]
__global__ __launch_bounds__(256)
void step3_kernel(const float* __restrict__ St, const _Float16* __restrict__ G,
                  float* __restrict__ NS)
{
  const int s = blockIdx.x;
  const int t = threadIdx.x;
  const int b = t >> 5, r = t & 31;
  float acc[10] = {0.f,0.f,0.f,0.f,0.f,0.f,0.f,0.f,0.f,0.f};
  for (int a = 0; a < 8; a++) {
    const _Float16* gp = G + ((size_t)((a * 8 + b) * 512 + s)) * 1024 + r;
    for (int l = 0; l < 32; l++) {
      const float g = (float)gp[l * 32];
      // St address is wave-uniform -> scalar loads
      const int off = __builtin_amdgcn_readfirstlane(s * 2560 + a * 320 + l * 10);
      const float* sv = St + off;
#pragma unroll
      for (int c = 0; c < 10; c++) acc[c] += g * sv[c];
    }
  }
  float* o = NS + (size_t)s * 2560 + t * 10;
#pragma unroll
  for (int c = 0; c < 10; c++) o[c] = acc[c];
}

// ---------------- out[s,c] = sum_{a,l} St[s,a,l,c] * GN[a][s][l]
__global__ __launch_bounds__(256)
void final_kernel(const float* __restrict__ St, const float* __restrict__ GN,
                  float* __restrict__ out)
{
  __shared__ float oc[16];
  const int s = blockIdx.x;
  const int t = threadIdx.x;
  if (t < 16) oc[t] = 0.f;
  __syncthreads();
  const int a = t >> 5, l = t & 31;
  const float gn = GN[((size_t)a * 512 + s) * 32 + l];
  const float* sv = St + (size_t)s * 2560 + a * 320 + l * 10;
#pragma unroll
  for (int c = 0; c < 10; c++) {
    float v = gn * sv[c];
#pragma unroll
    for (int o2 = 1; o2 < 64; o2 <<= 1) v += __shfl_xor(v, o2, 64);
    if ((t & 63) == 0) atomicAdd(&oc[c], v);
  }
  __syncthreads();
  if (t < 10) out[s * 10 + t] = oc[t];
}

// ---------------- prep kernels (cast/permute/pad; producers write ALL pad bytes) --------
__global__ void prep_xh(const float* __restrict__ x, _Float16* __restrict__ xh) {
  const int idx = blockIdx.x * 256 + threadIdx.x;   // 100352*64
  const int q = idx & 63, sp = idx >> 6;
  xh[idx] = (q < 48) ? (_Float16)x[sp * 48 + q] : (_Float16)0.f;
}

__global__ void prep_ckt(const float* __restrict__ cf, const float* __restrict__ cm,
                         const float* __restrict__ cl, _Float16* __restrict__ Ckt) {
  const int idx = blockIdx.x * 256 + threadIdx.x;   // 512*64
  const int q = idx & 63;
  const int row = idx >> 6;
  float v = 0.f;
  if (q < 48) {
    if (row < 8) v = cf[q * 8 + row];                                  // conv_first[q][b]
    else if (row < 392) {
      const int rr = row - 8;
      const int k = rr >> 6, ab = rr & 63, a = ab >> 3, b = ab & 7;
      v = cm[((k * 8 + a) * 48 + q) * 8 + b];                          // conv_mid[k][a][q][b]
    } else if (row < 400) v = cl[(row - 392) * 48 + q];                // conv_last[a][q]
  }
  Ckt[idx] = (_Float16)v;
}

__global__ void prep_akr(const float* __restrict__ tm, _Float16* __restrict__ Akr) {
  const int idx = blockIdx.x * 256 + threadIdx.x;   // 6*1024*224
  const int p = idx % 224;
  const int lr = (idx / 224) & 1023;
  const int k = idx / (224 * 1024);
  const int l = lr >> 5, r = lr & 31;
  float v = 0.f;
  if (p < 196) v = tm[(((k * 32 + l) * 196) + p) * 32 + r];            // train_mid[k][l][p][r]
  Akr[idx] = (_Float16)v;
}

__global__ void prep_bt0(const float* __restrict__ tf, _Float16* __restrict__ Bt0) {
  const int idx = blockIdx.x * 256 + threadIdx.x;   // 384*224
  const int p = idx % 224;
  const int n = idx / 224;
  float v = 0.f;
  if (n < 320 && p < 196) {
    const int r = n / 10, c = n % 10;
    v = tf[(c * 196 + p) * 32 + r];                                    // train_first[c][p][r]
  }
  Bt0[idx] = (_Float16)v;
}

__global__ void prep_btl(const float* __restrict__ tl, _Float16* __restrict__ Btl) {
  const int idx = blockIdx.x * 256 + threadIdx.x;   // 128*224
  const int p = idx % 224;
  const int n = idx / 224;
  float v = 0.f;
  if (n < 32 && p < 196) v = tl[n * 196 + p];                          // train_last[l][p]
  Btl[idx] = (_Float16)v;
}

__global__ void zero_mtpad(_Float16* __restrict__ Mt) {
  const int idx = blockIdx.x * 256 + threadIdx.x;   // 400*512
  if (idx < 204800) {
    _Float16* p = Mt + (size_t)idx * KP + 196;
#pragma unroll
    for (int j = 0; j < 28; j++) p[j] = (_Float16)0.f;
  }
}

extern "C" void kernel_launch(void* const* d_in, const int* in_sizes, int n_in,
                              void* d_out, int out_size, void* d_ws, size_t ws_size,
                              hipStream_t stream)
{
  const float* x  = (const float*)d_in[0];
  const float* cf = (const float*)d_in[1];
  const float* cm = (const float*)d_in[2];
  const float* cl = (const float*)d_in[3];
  const float* tf = (const float*)d_in[4];
  const float* tm = (const float*)d_in[5];
  const float* tl = (const float*)d_in[6];
  float* out = (float*)d_out;

  char* w = (char*)d_ws;
  auto alloc = [&](size_t bytes) { char* p = w; w += (bytes + 255) & ~(size_t)255; return p; };
  _Float16* xh  = (_Float16*)alloc(100352ull * 64 * 2);   // 12.8 MB
  _Float16* Ckt = (_Float16*)alloc(512ull * 64 * 2);      // 64 KB
  _Float16* Mt  = (_Float16*)alloc(400ull * 512 * KP * 2);// 91.8 MB
  _Float16* Akr = (_Float16*)alloc(6ull * 1024 * KP * 2); // 2.75 MB
  _Float16* Bt0 = (_Float16*)alloc(384ull * KP * 2);
  _Float16* Btl = (_Float16*)alloc(128ull * KP * 2);
  _Float16* G   = (_Float16*)alloc(32768ull * 1024 * 2);  // 67 MB
  float* stA    = (float*)alloc(512ull * 2560 * 4);
  float* stB    = (float*)alloc(512ull * 2560 * 4);
  float* GN     = (float*)alloc(4096ull * 32 * 4);
  (void)ws_size; (void)in_sizes; (void)n_in; (void)out_size;  // total ws use: ~186 MB

  prep_xh <<<25088, 256, 0, stream>>>(x, xh);
  prep_ckt<<<  128, 256, 0, stream>>>(cf, cm, cl, Ckt);
  prep_akr<<< 5376, 256, 0, stream>>>(tm, Akr);
  prep_bt0<<<  336, 256, 0, stream>>>(tf, Bt0);
  prep_btl<<<  112, 256, 0, stream>>>(tl, Btl);
  zero_mtpad<<<800, 256, 0, stream>>>(Mt);

  // all carriages' conv contractions in one GEMM: [512 rows][100352 (s,p)]
  gemm_mfma<QP, 0><<<dim3(784, 4), 256, 0, stream>>>(Ckt, xh, Mt);
  // initial state: [4096 (b,s)][384->320 (r,c)]
  gemm_mfma<KP, 2><<<dim3(3, 32), 256, 0, stream>>>(Mt, Bt0, stA);

  float* sIn = stA; float* sOut = stB;
  for (int k = 0; k < 6; k++) {
    gemm_mfma<KP, 1><<<dim3(8, 256), 256, 0, stream>>>(
        Mt + (size_t)(8 + 64 * k) * 512 * KP, Akr + (size_t)k * 1024 * KP, G);
    step3_kernel<<<512, 256, 0, stream>>>(sIn, G, sOut);
    float* t2 = sIn; sIn = sOut; sOut = t2;
  }
  // last carriage: GN[a][s][l]
  gemm_mfma<KP, 3><<<dim3(1, 32), 256, 0, stream>>>(Mt + (size_t)392 * 512 * KP, Btl, GN);
  final_kernel<<<512, 256, 0, stream>>>(sIn, GN, out);
}

// Round 2
// 424.596 us; speedup vs baseline: 1.2768x; 1.2768x over previous
//
#include <hip/hip_runtime.h>

// TensorConvolutionTrainLayer: S=512,P=196,Q=48,CB=8,R=32,C=10,N=8
// R2: fused chain kernel — G never hits global memory. Block = one sample.
//   GEMM1 (MODE0): Mt[row][(s,p)] = Ckt[row][q] @ xh[(s,p)][q]^T  (all 8 carriages)
//   state0 (MODE2), GN (MODE3): templated MFMA GEMM, per-mode epilogue
//   chain_kernel: 6x { G-tile MFMA in regs -> contract with LDS state } + final output

typedef _Float16 half8 __attribute__((ext_vector_type(8)));
typedef float floatx4 __attribute__((ext_vector_type(4)));

#define KP 224   // P=196 padded to 7*32
#define QP 64    // Q=48 padded to 2*32
#define NROWS 400
#define BM 128
#define BN 128
#define BK 32

__device__ __forceinline__ void gld_lds16(const void* g, void* l) {
  __builtin_amdgcn_global_load_lds((const __attribute__((address_space(1))) void*)g,
                                   (__attribute__((address_space(3))) void*)l, 16, 0, 0);
}

// ---------------- generic MFMA GEMM (proven in R1) ----------------
template<int K, int MODE>
__global__ __launch_bounds__(256)
void gemm_mfma(const _Float16* __restrict__ A, const _Float16* __restrict__ Bt,
               void* __restrict__ outp)
{
  __shared__ __align__(16) _Float16 Ash[BM * BK];
  __shared__ __align__(16) _Float16 Bsh[BN * BK];
  const int tid  = threadIdx.x;
  const int wave = tid >> 6;
  const int lane = tid & 63;
  const int m0 = blockIdx.y * BM;
  const int n0 = blockIdx.x * BN;
  const int wm = (wave >> 1) * 64;
  const int wn = (wave & 1) * 64;
  const int fr = lane & 15;
  const int fq = lane >> 4;

  floatx4 acc[4][4] = {};

  for (int kt = 0; kt < K; kt += BK) {
    __syncthreads();
#pragma unroll
    for (int j = 0; j < 2; j++) {
      const int c   = j * 256 + tid;
      const int row = c >> 2;
      const int ko  = (c & 3) * 8;
      gld_lds16(A  + (size_t)(m0 + row) * K + kt + ko,
                (char*)Ash + (size_t)(j * 256 + wave * 64) * 16);
      gld_lds16(Bt + (size_t)(n0 + row) * K + kt + ko,
                (char*)Bsh + (size_t)(j * 256 + wave * 64) * 16);
    }
    __syncthreads();
    half8 af[4], bf[4];
#pragma unroll
    for (int i = 0; i < 4; i++)
      af[i] = *(const half8*)&Ash[(wm + i * 16 + fr) * BK + fq * 8];
#pragma unroll
    for (int i = 0; i < 4; i++)
      bf[i] = *(const half8*)&Bsh[(wn + i * 16 + fr) * BK + fq * 8];
#pragma unroll
    for (int i = 0; i < 4; i++)
#pragma unroll
      for (int j = 0; j < 4; j++)
        acc[i][j] = __builtin_amdgcn_mfma_f32_16x16x32_f16(af[i], bf[j], acc[i][j], 0, 0, 0);
  }

#pragma unroll
  for (int i = 0; i < 4; i++) {
#pragma unroll
    for (int j = 0; j < 4; j++) {
#pragma unroll
      for (int r = 0; r < 4; r++) {
        const int m = m0 + wm + i * 16 + fq * 4 + r;
        const int n = n0 + wn + j * 16 + fr;
        const float v = acc[i][j][r];
        if constexpr (MODE == 0) {
          if (m < NROWS) {
            const unsigned s = (unsigned)n / 196u;
            const unsigned p = (unsigned)n - s * 196u;
            ((_Float16*)outp)[((size_t)m * 512 + s) * KP + p] = (_Float16)v;
          }
        } else if constexpr (MODE == 2) {
          // state0: m = b*512+s, n = r*10+c -> St0[s][b*320 + r*10 + c]
          if (n < 320)
            ((float*)outp)[(size_t)(m & 511) * 2560 + (m >> 9) * 320 + n] = v;
        } else {
          // GN: m = a*512+s, n = l -> GN[a][s][l]
          if (n < 32)
            ((float*)outp)[(size_t)m * 32 + n] = v;
        }
      }
    }
  }
}

// ---------------- fused chain kernel ----------------
// block = sample s (512 blocks, 256 thr = 4 waves, 2 blocks/CU).
// Per step k: stage A = Mt rows [8+64k, +64) for this s into LDS (stride 232);
// 8 chunks of N=128 Akr cols; wave w in chunk cc computes G[ab 0..64][l=4cc+w][r 0..32)
// in MFMA accs, contracts vs St (LDS) into 80 reg accumulators; cross-lane + LDS reduce.
__global__ __launch_bounds__(256, 2)
void chain_kernel(const _Float16* __restrict__ Mt, const _Float16* __restrict__ Akr,
                  const float* __restrict__ St0, const float* __restrict__ GN,
                  float* __restrict__ out)
{
  __shared__ __align__(16) _Float16 Ash[64 * 232];      // 29696 B
  __shared__ __align__(16) float St[8 * 32 * 12];       // 12288 B (c padded 10->12)
  __shared__ __align__(16) float NSp[2][8 * 32 * 10];   // 20480 B
  __shared__ float oc[10];

  const int tid  = threadIdx.x;
  const int wave = tid >> 6;
  const int lane = tid & 63;
  const int s    = blockIdx.x;
  const int fr   = lane & 15;
  const int fq   = lane >> 4;
  const int fqh  = fq >> 1;       // a parity bit
  const int fql  = fq & 1;        // b high bit

  // initial state: St0[s][b*320 + r*10 + c] -> St[(a=b)*384 + (l=r)*12 + c]
  {
    const float* src = St0 + (size_t)s * 2560 + tid * 10;
    float* dst = &St[tid * 12];
#pragma unroll
    for (int c = 0; c < 10; c++) dst[c] = src[c];
    if (tid < 10) oc[tid] = 0.f;
  }

  for (int k = 0; k < 6; k++) {
    __syncthreads();
    // ---- stage A: 64 rows x 224 halfs (+8 slack), LDS stride 232 = 29 x 16B ----
    const _Float16* Abase = Mt + ((size_t)(8 + 64 * k) * 512 + s) * 224;
#pragma unroll
    for (int it = 0; it < 8; it++) {
      const int c = it * 256 + tid;
      if (c < 1856) {  // 64 rows * 29 chunks; wave-uniform predicate per iteration
        gld_lds16(Abase + (size_t)(c / 29) * 114688 + (c % 29) * 8,
                  (char*)Ash + (size_t)(it * 256 + wave * 64) * 16);
      }
    }
    float ns[2][4][10];
#pragma unroll
    for (int ni = 0; ni < 2; ni++)
#pragma unroll
      for (int rg = 0; rg < 4; rg++)
#pragma unroll
        for (int c = 0; c < 10; c++) ns[ni][rg][c] = 0.f;
    __syncthreads();

    const _Float16* Bk = Akr + (size_t)k * 1024 * 224;
    for (int cc = 0; cc < 8; cc++) {
      floatx4 acc[4][2] = {};
      const _Float16* Bb = Bk + (size_t)(cc * 128 + wave * 32) * 224;
#pragma unroll
      for (int kt = 0; kt < 7; kt++) {
        half8 af[4], bf[2];
#pragma unroll
        for (int mi = 0; mi < 4; mi++)
          af[mi] = *(const half8*)&Ash[(mi * 16 + fr) * 232 + kt * 32 + fq * 8];
#pragma unroll
        for (int ni = 0; ni < 2; ni++)
          bf[ni] = *(const half8*)(Bb + (size_t)(ni * 16 + fr) * 224 + kt * 32 + fq * 8);
#pragma unroll
        for (int mi = 0; mi < 4; mi++)
#pragma unroll
          for (int ni = 0; ni < 2; ni++)
            acc[mi][ni] = __builtin_amdgcn_mfma_f32_16x16x32_f16(af[mi], bf[ni], acc[mi][ni], 0, 0, 0);
      }
      // ---- contract G (regs) with St (LDS): l = cc*4 + wave ----
      const int l = cc * 4 + wave;
#pragma unroll
      for (int mi = 0; mi < 4; mi++) {
        const float* stp = &St[(2 * mi + fqh) * 384 + l * 12];
        const floatx4 s0 = *(const floatx4*)stp;
        const floatx4 s1 = *(const floatx4*)(stp + 4);
        const floatx4 s2 = *(const floatx4*)(stp + 8);   // c=10,11 are pad (in-bounds)
        float stv[10] = {s0[0], s0[1], s0[2], s0[3], s1[0], s1[1], s1[2], s1[3], s2[0], s2[1]};
#pragma unroll
        for (int ni = 0; ni < 2; ni++)
#pragma unroll
          for (int rg = 0; rg < 4; rg++) {
            const float g = acc[mi][ni][rg];
#pragma unroll
            for (int c = 0; c < 10; c++) ns[ni][rg][c] += g * stv[c];
          }
      }
    }

    // ---- reduce: fold a-parity across lane^32, then 4 waves -> 2 LDS regions -> St ----
#pragma unroll
    for (int ni = 0; ni < 2; ni++)
#pragma unroll
      for (int rg = 0; rg < 4; rg++)
#pragma unroll
        for (int c = 0; c < 10; c++)
          ns[ni][rg][c] += __shfl_xor(ns[ni][rg][c], 32, 64);

    if (wave < 2 && fq < 2) {
#pragma unroll
      for (int ni = 0; ni < 2; ni++)
#pragma unroll
        for (int rg = 0; rg < 4; rg++)
#pragma unroll
          for (int c = 0; c < 10; c++)
            NSp[wave][((fql * 4 + rg) * 32 + (ni * 16 + fr)) * 10 + c] = ns[ni][rg][c];
    }
    __syncthreads();
    if (wave >= 2 && fq < 2) {
#pragma unroll
      for (int ni = 0; ni < 2; ni++)
#pragma unroll
        for (int rg = 0; rg < 4; rg++)
#pragma unroll
          for (int c = 0; c < 10; c++) {
            const int idx = ((fql * 4 + rg) * 32 + (ni * 16 + fr)) * 10 + c;
            NSp[wave - 2][idx] += ns[ni][rg][c];
          }
    }
    __syncthreads();
    {
      float* d = &St[tid * 12];
      const float* p0 = &NSp[0][tid * 10];
      const float* p1 = &NSp[1][tid * 10];
#pragma unroll
      for (int c = 0; c < 10; c++) d[c] = p0[c] + p1[c];
    }
  }
  __syncthreads();

  // ---- final: out[s,c] = sum_{a,l} St[a,l,c] * GN[a][s][l] ----
  {
    const int a = tid >> 5, l = tid & 31;
    const float gn = GN[((size_t)a * 512 + s) * 32 + l];
    const float* stp = &St[tid * 12];
#pragma unroll
    for (int c = 0; c < 10; c++) {
      float v = gn * stp[c];
#pragma unroll
      for (int o2 = 1; o2 < 64; o2 <<= 1) v += __shfl_xor(v, o2, 64);
      if (lane == 0) atomicAdd(&oc[c], v);
    }
    __syncthreads();
    if (tid < 10) out[(size_t)s * 10 + tid] = oc[tid];
  }
}

// ---------------- prep kernels (unchanged from R1) ----------------
__global__ void prep_xh(const float* __restrict__ x, _Float16* __restrict__ xh) {
  const int idx = blockIdx.x * 256 + threadIdx.x;
  const int q = idx & 63, sp = idx >> 6;
  xh[idx] = (q < 48) ? (_Float16)x[sp * 48 + q] : (_Float16)0.f;
}

__global__ void prep_ckt(const float* __restrict__ cf, const float* __restrict__ cm,
                         const float* __restrict__ cl, _Float16* __restrict__ Ckt) {
  const int idx = blockIdx.x * 256 + threadIdx.x;
  const int q = idx & 63;
  const int row = idx >> 6;
  float v = 0.f;
  if (q < 48) {
    if (row < 8) v = cf[q * 8 + row];
    else if (row < 392) {
      const int rr = row - 8;
      const int k = rr >> 6, ab = rr & 63, a = ab >> 3, b = ab & 7;
      v = cm[((k * 8 + a) * 48 + q) * 8 + b];
    } else if (row < 400) v = cl[(row - 392) * 48 + q];
  }
  Ckt[idx] = (_Float16)v;
}

__global__ void prep_akr(const float* __restrict__ tm, _Float16* __restrict__ Akr) {
  const int idx = blockIdx.x * 256 + threadIdx.x;
  const int p = idx % 224;
  const int lr = (idx / 224) & 1023;
  const int k = idx / (224 * 1024);
  const int l = lr >> 5, r = lr & 31;
  float v = 0.f;
  if (p < 196) v = tm[(((k * 32 + l) * 196) + p) * 32 + r];
  Akr[idx] = (_Float16)v;
}

__global__ void prep_bt0(const float* __restrict__ tf, _Float16* __restrict__ Bt0) {
  const int idx = blockIdx.x * 256 + threadIdx.x;
  const int p = idx % 224;
  const int n = idx / 224;
  float v = 0.f;
  if (n < 320 && p < 196) {
    const int r = n / 10, c = n % 10;
    v = tf[(c * 196 + p) * 32 + r];
  }
  Bt0[idx] = (_Float16)v;
}

__global__ void prep_btl(const float* __restrict__ tl, _Float16* __restrict__ Btl) {
  const int idx = blockIdx.x * 256 + threadIdx.x;
  const int p = idx % 224;
  const int n = idx / 224;
  float v = 0.f;
  if (n < 32 && p < 196) v = tl[n * 196 + p];
  Btl[idx] = (_Float16)v;
}

__global__ void zero_mtpad(_Float16* __restrict__ Mt) {
  const int idx = blockIdx.x * 256 + threadIdx.x;
  if (idx < 204800) {
    _Float16* p = Mt + (size_t)idx * KP + 196;
#pragma unroll
    for (int j = 0; j < 28; j++) p[j] = (_Float16)0.f;
  }
}

extern "C" void kernel_launch(void* const* d_in, const int* in_sizes, int n_in,
                              void* d_out, int out_size, void* d_ws, size_t ws_size,
                              hipStream_t stream)
{
  const float* x  = (const float*)d_in[0];
  const float* cf = (const float*)d_in[1];
  const float* cm = (const float*)d_in[2];
  const float* cl = (const float*)d_in[3];
  const float* tf = (const float*)d_in[4];
  const float* tm = (const float*)d_in[5];
  const float* tl = (const float*)d_in[6];
  float* out = (float*)d_out;

  char* w = (char*)d_ws;
  auto alloc = [&](size_t bytes) { char* p = w; w += (bytes + 255) & ~(size_t)255; return p; };
  _Float16* xh  = (_Float16*)alloc(100352ull * 64 * 2);     // 12.8 MB
  _Float16* Ckt = (_Float16*)alloc(512ull * 64 * 2);
  _Float16* Mt  = (_Float16*)alloc(400ull * 512 * KP * 2);  // 91.8 MB
  _Float16* Akr = (_Float16*)alloc(6ull * 1024 * KP * 2);   // 2.75 MB
  _Float16* Bt0 = (_Float16*)alloc(384ull * KP * 2);
  _Float16* Btl = (_Float16*)alloc(128ull * KP * 2);
  float* stA    = (float*)alloc(512ull * 2560 * 4);         // 5.2 MB
  float* GN     = (float*)alloc(4096ull * 32 * 4);
  (void)ws_size; (void)in_sizes; (void)n_in; (void)out_size;

  prep_xh <<<25088, 256, 0, stream>>>(x, xh);
  prep_ckt<<<  128, 256, 0, stream>>>(cf, cm, cl, Ckt);
  prep_akr<<< 5376, 256, 0, stream>>>(tm, Akr);
  prep_bt0<<<  336, 256, 0, stream>>>(tf, Bt0);
  prep_btl<<<  112, 256, 0, stream>>>(tl, Btl);
  zero_mtpad<<<800, 256, 0, stream>>>(Mt);

  gemm_mfma<QP, 0><<<dim3(784, 4), 256, 0, stream>>>(Ckt, xh, Mt);
  gemm_mfma<KP, 2><<<dim3(3, 32), 256, 0, stream>>>(Mt, Bt0, stA);
  gemm_mfma<KP, 3><<<dim3(1, 32), 256, 0, stream>>>(Mt + (size_t)392 * 512 * KP, Btl, GN);

  chain_kernel<<<512, 256, 0, stream>>>(Mt, Akr, stA, GN, out);
}